// Round 17
// baseline (315.908 us; speedup 1.0000x reference)
//
#include <hip/hip_runtime.h>
#include <hip/hip_bf16.h>

#define HEADS 4
#define NEG 0.2f
#define SHIFT 7
#define BKT 128           // nodes per bucket = 1<<SHIFT

typedef float fv4 __attribute__((ext_vector_type(4)));
typedef unsigned short uv4 __attribute__((ext_vector_type(4)));
typedef unsigned short uv8 __attribute__((ext_vector_type(8)));

static __device__ __forceinline__ unsigned short f2bf(float f) {
  unsigned u = __float_as_uint(f);
  u += 0x7FFFu + ((u >> 16) & 1u);   // round-to-nearest-even
  return (unsigned short)(u >> 16);
}
static __device__ __forceinline__ float bf2f(unsigned short h) {
  return __uint_as_float((unsigned)h << 16);
}

// ---- pass1: radix-bin edges by dst>>SHIFT, packed (src<<SHIFT|dst_local) ----
// grid == nb exactly: one 4096-edge batch per block (512-block grid had a
// 2x straggler tail: 270 blocks did 2 batches).
__global__ __launch_bounds__(256) void k_bin(const int* __restrict__ ei, int E,
                                             int K, int CAP,
                                             int* __restrict__ cursor,
                                             int* __restrict__ bins) {
  __shared__ int lcnt[1024];
  __shared__ int gbase[1024];
  const int t = threadIdx.x;
  const int e0 = (int)blockIdx.x << 12;
  for (int i = t; i < K; i += 256) lcnt[i] = 0;
  __syncthreads();
  int sreg[16], dreg[16], rank[16];
#pragma unroll
  for (int j = 0; j < 16; ++j) {
    int e = e0 + j * 256 + t;
    dreg[j] = -1;
    if (e < E) {
      sreg[j] = ei[e];
      dreg[j] = ei[E + e];
      rank[j] = atomicAdd(&lcnt[dreg[j] >> SHIFT], 1);
    }
  }
  __syncthreads();
  for (int i = t; i < K; i += 256)
    gbase[i] = (lcnt[i] > 0) ? atomicAdd(&cursor[i], lcnt[i]) : 0;
  __syncthreads();
#pragma unroll
  for (int j = 0; j < 16; ++j) {
    if (dreg[j] >= 0) {
      int b = dreg[j] >> SHIFT;
      int slot = gbase[b] + rank[j];
      if (slot < CAP)
        bins[(size_t)b * CAP + slot] = (sreg[j] << SHIFT) | (dreg[j] & (BKT - 1));
    }
  }
}

// ---- pass2: LDS counting-sort per bucket, in-place, coalesced writeback ----
__global__ __launch_bounds__(256) void k_sort(int* __restrict__ bins,
                                              const int* __restrict__ cursor,
                                              int CAP, int N,
                                              int* __restrict__ rowbase,
                                              int* __restrict__ deg) {
  __shared__ int ebuf[6144];
  __shared__ int sbuf[6144];
  __shared__ int hist[BKT], pre[BKT], cur[BKT];
  const int b = blockIdx.x;
  const int base = b << SHIFT;
  const int t = threadIdx.x;
  int total = cursor[b]; if (total > CAP) total = CAP;
  int* gsrc = bins + (size_t)b * CAP;
  for (int i = t; i < total; i += 256) ebuf[i] = gsrc[i];
  if (t < BKT) hist[t] = 0;
  __syncthreads();
  for (int i = t; i < total; i += 256) atomicAdd(&hist[ebuf[i] & (BKT - 1)], 1);
  __syncthreads();
  if (t < BKT) pre[t] = hist[t];
  __syncthreads();
  for (int off = 1; off < BKT; off <<= 1) {
    int v = (t < BKT && t >= off) ? pre[t - off] : 0;
    __syncthreads();
    if (t < BKT) pre[t] += v;
    __syncthreads();
  }
  if (t < BKT) {
    int ex = pre[t] - hist[t];      // exclusive prefix
    cur[t] = ex;
    int n = base + t;
    if (n < N) { rowbase[n] = b * CAP + ex; deg[n] = hist[t]; }
  }
  __syncthreads();
  for (int i = t; i < total; i += 256) {
    int pk = ebuf[i];
    int r = atomicAdd(&cur[pk & (BKT - 1)], 1);
    sbuf[r] = pk >> SHIFT;           // store plain src id
  }
  __syncthreads();
  for (int i = t; i < total; i += 256) gsrc[i] = sbuf[i];
}

// ---------------- GEMM1: g1b = bf16(x @ W1), fused e-scores ----------------
// 64-row tile (25.4 KB LDS, 6 blocks/CU) + register prefetch of chunk k+1.
__global__ __launch_bounds__(256) void k_gemm1(const float* __restrict__ x,
                                               const float* __restrict__ W,
                                               const float* __restrict__ a1s,
                                               const float* __restrict__ a1d,
                                               unsigned short* __restrict__ g1b,
                                               float* __restrict__ e1s,
                                               float* __restrict__ e1d, int N) {
  __shared__ __align__(16) float xs[64][68];
  __shared__ __align__(16) float ws[64][32];
  const int t = threadIdx.x;
  const int n0 = blockIdx.x * 64;
  const int nl = t >> 2;   // node within tile
  const int cg = t & 3;    // head, cols 8cg..8cg+7
  float acc[8];
#pragma unroll
  for (int j = 0; j < 8; ++j) acc[j] = 0.f;
  const int r = t >> 4;
  const int kk = (t & 15) << 2;
  fv4 xr[4];
  float4 wr0, wr1;
#pragma unroll
  for (int i = 0; i < 4; ++i) {
    int gn = n0 + r + i * 16;
    fv4 v = {0.f, 0.f, 0.f, 0.f};
    if (gn < N) v = __builtin_nontemporal_load((const fv4*)(x + (size_t)gn * 512 + kk));
    xr[i] = v;
  }
  wr0 = ((const float4*)W)[t];
  wr1 = ((const float4*)W)[t + 256];
  for (int kc = 0; kc < 512; kc += 64) {
    __syncthreads();
#pragma unroll
    for (int i = 0; i < 4; ++i) *(fv4*)(&xs[r + i * 16][kk]) = xr[i];
    ((float4*)ws)[t] = wr0;
    ((float4*)ws)[t + 256] = wr1;
    __syncthreads();
    const int kn = kc + 64;
    if (kn < 512) {
#pragma unroll
      for (int i = 0; i < 4; ++i) {
        int gn = n0 + r + i * 16;
        fv4 v = {0.f, 0.f, 0.f, 0.f};
        if (gn < N) v = __builtin_nontemporal_load((const fv4*)(x + (size_t)gn * 512 + kn + kk));
        xr[i] = v;
      }
      wr0 = ((const float4*)(W + kn * 32))[t];
      wr1 = ((const float4*)(W + kn * 32))[t + 256];
    }
#pragma unroll
    for (int k = 0; k < 64; ++k) {
      float xv = xs[nl][k];
      float4 w0 = *(const float4*)(&ws[k][cg * 8]);
      float4 w1 = *(const float4*)(&ws[k][cg * 8 + 4]);
      acc[0] = fmaf(xv, w0.x, acc[0]);
      acc[1] = fmaf(xv, w0.y, acc[1]);
      acc[2] = fmaf(xv, w0.z, acc[2]);
      acc[3] = fmaf(xv, w0.w, acc[3]);
      acc[4] = fmaf(xv, w1.x, acc[4]);
      acc[5] = fmaf(xv, w1.y, acc[5]);
      acc[6] = fmaf(xv, w1.z, acc[6]);
      acc[7] = fmaf(xv, w1.w, acc[7]);
    }
  }
  int gn = n0 + nl;
  if (gn < N) {
    uv8 pk;
#pragma unroll
    for (int j = 0; j < 8; ++j) pk[j] = f2bf(acc[j]);
    *(uv8*)(g1b + (size_t)gn * 32 + cg * 8) = pk;
    const float* as = a1s + cg * 8;
    const float* ad = a1d + cg * 8;
    float s = 0.f, d = 0.f;
#pragma unroll
    for (int j = 0; j < 8; ++j) { s = fmaf(acc[j], as[j], s); d = fmaf(acc[j], ad[j], d); }
    e1s[gn * 4 + cg] = s;
    e1d[gn * 4 + cg] = d;
  }
}

// ---- conv1 aggregation: 8 lanes per node, gather-only, 4x unrolled ----
__global__ __launch_bounds__(256) void k_agg1(const int* __restrict__ rowbase,
                                              const int* __restrict__ deg,
                                              const int* __restrict__ csr,
                                              const float* __restrict__ e1s,
                                              const float* __restrict__ e1d,
                                              const unsigned short* __restrict__ g1b,
                                              const float* __restrict__ b1,
                                              float* __restrict__ h1, int N) {
  int gid = blockIdx.x * blockDim.x + threadIdx.x;
  if (gid >= N * 8) return;
  int n = gid >> 3, cg = gid & 7, hd = cg >> 1;
  float edn = e1d[n * 4 + hd];
  // self-loop
  float s = e1s[n * 4 + hd] + edn;
  float p = __expf(s > 0.f ? s : NEG * s);
  uv4 hv = *(const uv4*)(g1b + (size_t)n * 32 + cg * 4);
  float4 acc = make_float4(p * bf2f(hv.x), p * bf2f(hv.y), p * bf2f(hv.z), p * bf2f(hv.w));
  float den = p;
  int beg = rowbase[n], len = deg[n];
  const int* row = csr + beg;
  int i = 0;
  for (; i + 4 <= len; i += 4) {           // 4 independent gathers in flight
    int s0 = row[i], s1 = row[i + 1], s2 = row[i + 2], s3 = row[i + 3];
    float ea = e1s[s0 * 4 + hd] + edn;
    float eb = e1s[s1 * 4 + hd] + edn;
    float ec = e1s[s2 * 4 + hd] + edn;
    float ed = e1s[s3 * 4 + hd] + edn;
    uv4 v0 = *(const uv4*)(g1b + (size_t)s0 * 32 + cg * 4);
    uv4 v1 = *(const uv4*)(g1b + (size_t)s1 * 32 + cg * 4);
    uv4 v2 = *(const uv4*)(g1b + (size_t)s2 * 32 + cg * 4);
    uv4 v3 = *(const uv4*)(g1b + (size_t)s3 * 32 + cg * 4);
    float p0 = __expf(ea > 0.f ? ea : NEG * ea);
    float p1 = __expf(eb > 0.f ? eb : NEG * eb);
    float p2 = __expf(ec > 0.f ? ec : NEG * ec);
    float p3 = __expf(ed > 0.f ? ed : NEG * ed);
    acc.x = fmaf(p0, bf2f(v0.x), acc.x);
    acc.y = fmaf(p0, bf2f(v0.y), acc.y);
    acc.z = fmaf(p0, bf2f(v0.z), acc.z);
    acc.w = fmaf(p0, bf2f(v0.w), acc.w);
    acc.x = fmaf(p1, bf2f(v1.x), acc.x);
    acc.y = fmaf(p1, bf2f(v1.y), acc.y);
    acc.z = fmaf(p1, bf2f(v1.z), acc.z);
    acc.w = fmaf(p1, bf2f(v1.w), acc.w);
    acc.x = fmaf(p2, bf2f(v2.x), acc.x);
    acc.y = fmaf(p2, bf2f(v2.y), acc.y);
    acc.z = fmaf(p2, bf2f(v2.z), acc.z);
    acc.w = fmaf(p2, bf2f(v2.w), acc.w);
    acc.x = fmaf(p3, bf2f(v3.x), acc.x);
    acc.y = fmaf(p3, bf2f(v3.y), acc.y);
    acc.z = fmaf(p3, bf2f(v3.z), acc.z);
    acc.w = fmaf(p3, bf2f(v3.w), acc.w);
    den += p0 + p1 + p2 + p3;
  }
  for (; i < len; ++i) {
    int s0 = row[i];
    float ea = e1s[s0 * 4 + hd] + edn;
    float p0 = __expf(ea > 0.f ? ea : NEG * ea);
    uv4 v0 = *(const uv4*)(g1b + (size_t)s0 * 32 + cg * 4);
    acc.x = fmaf(p0, bf2f(v0.x), acc.x);
    acc.y = fmaf(p0, bf2f(v0.y), acc.y);
    acc.z = fmaf(p0, bf2f(v0.z), acc.z);
    acc.w = fmaf(p0, bf2f(v0.w), acc.w);
    den += p0;
  }
  float inv = 1.f / den;
  const float* bp = b1 + cg * 4;
  float4 o;
  o.x = fmaxf(fmaf(acc.x, inv, bp[0]), 0.f);
  o.y = fmaxf(fmaf(acc.y, inv, bp[1]), 0.f);
  o.z = fmaxf(fmaf(acc.z, inv, bp[2]), 0.f);
  o.w = fmaxf(fmaf(acc.w, inv, bp[3]), 0.f);
  *(float4*)(h1 + (size_t)gid * 4) = o;
}

// ---- GEMM2 (fused e2 scores): g2b = bf16(h1 @ W2) ----
__global__ __launch_bounds__(256) void k_gemm2(const float* __restrict__ h1,
                                               const float* __restrict__ W2,
                                               const float* __restrict__ a2s_,
                                               const float* __restrict__ a2d_,
                                               unsigned short* __restrict__ g2b,
                                               float* __restrict__ e2s,
                                               float* __restrict__ e2d, int N) {
  __shared__ __align__(16) float hs[64][36];
  __shared__ __align__(16) float ws[32][16];
  const int t = threadIdx.x;
  const int n0 = blockIdx.x * 64;
  {
    int row = t >> 3, c4 = (t & 7) * 4;
#pragma unroll
    for (int i = 0; i < 2; ++i) {
      int rr = row + i * 32;
      int gn = n0 + rr;
      float4 v = make_float4(0.f, 0.f, 0.f, 0.f);
      if (gn < N) v = *(const float4*)(h1 + (size_t)gn * 32 + c4);
      *(float4*)(&hs[rr][c4]) = v;
    }
    if (t < 128) ((float4*)ws)[t] = ((const float4*)W2)[t];
  }
  __syncthreads();
  const int nl = t >> 2, cg = t & 3;   // head = cg
  float acc[4] = {0.f, 0.f, 0.f, 0.f};
#pragma unroll
  for (int k = 0; k < 32; ++k) {
    float xv = hs[nl][k];
    float4 w = *(const float4*)(&ws[k][cg * 4]);
    acc[0] = fmaf(xv, w.x, acc[0]);
    acc[1] = fmaf(xv, w.y, acc[1]);
    acc[2] = fmaf(xv, w.z, acc[2]);
    acc[3] = fmaf(xv, w.w, acc[3]);
  }
  int gn = n0 + nl;
  if (gn < N) {
    uv4 pk;
#pragma unroll
    for (int j = 0; j < 4; ++j) pk[j] = f2bf(acc[j]);
    *(uv4*)(g2b + (size_t)gn * 16 + cg * 4) = pk;
    const float* as = a2s_ + cg * 4;
    const float* ad = a2d_ + cg * 4;
    e2s[gn * 4 + cg] = acc[0] * as[0] + acc[1] * as[1] + acc[2] * as[2] + acc[3] * as[3];
    e2d[gn * 4 + cg] = acc[0] * ad[0] + acc[1] * ad[1] + acc[2] * ad[2] + acc[3] * ad[3];
  }
}

// ---- conv2 aggregation: 4 lanes per node, gather-only, 4x unrolled ----
__global__ __launch_bounds__(256) void k_agg2(const int* __restrict__ rowbase,
                                              const int* __restrict__ deg,
                                              const int* __restrict__ csr,
                                              const float* __restrict__ e2s,
                                              const float* __restrict__ e2d,
                                              const unsigned short* __restrict__ g2b,
                                              const float* __restrict__ b2,
                                              float* __restrict__ h2, int N) {
  int gid = blockIdx.x * blockDim.x + threadIdx.x;
  if (gid >= N * 4) return;
  int n = gid >> 2, hd = gid & 3;
  float edn = e2d[n * 4 + hd];
  float s = e2s[n * 4 + hd] + edn;
  float p = __expf(s > 0.f ? s : NEG * s);
  uv4 hv = *(const uv4*)(g2b + (size_t)n * 16 + hd * 4);
  float4 acc = make_float4(p * bf2f(hv.x), p * bf2f(hv.y), p * bf2f(hv.z), p * bf2f(hv.w));
  float den = p;
  int beg = rowbase[n], len = deg[n];
  const int* row = csr + beg;
  int i = 0;
  for (; i + 4 <= len; i += 4) {
    int s0 = row[i], s1 = row[i + 1], s2 = row[i + 2], s3 = row[i + 3];
    float ea = e2s[s0 * 4 + hd] + edn;
    float eb = e2s[s1 * 4 + hd] + edn;
    float ec = e2s[s2 * 4 + hd] + edn;
    float ed = e2s[s3 * 4 + hd] + edn;
    uv4 v0 = *(const uv4*)(g2b + (size_t)s0 * 16 + hd * 4);
    uv4 v1 = *(const uv4*)(g2b + (size_t)s1 * 16 + hd * 4);
    uv4 v2 = *(const uv4*)(g2b + (size_t)s2 * 16 + hd * 4);
    uv4 v3 = *(const uv4*)(g2b + (size_t)s3 * 16 + hd * 4);
    float p0 = __expf(ea > 0.f ? ea : NEG * ea);
    float p1 = __expf(eb > 0.f ? eb : NEG * eb);
    float p2 = __expf(ec > 0.f ? ec : NEG * ec);
    float p3 = __expf(ed > 0.f ? ed : NEG * ed);
    acc.x = fmaf(p0, bf2f(v0.x), acc.x);
    acc.y = fmaf(p0, bf2f(v0.y), acc.y);
    acc.z = fmaf(p0, bf2f(v0.z), acc.z);
    acc.w = fmaf(p0, bf2f(v0.w), acc.w);
    acc.x = fmaf(p1, bf2f(v1.x), acc.x);
    acc.y = fmaf(p1, bf2f(v1.y), acc.y);
    acc.z = fmaf(p1, bf2f(v1.z), acc.z);
    acc.w = fmaf(p1, bf2f(v1.w), acc.w);
    acc.x = fmaf(p2, bf2f(v2.x), acc.x);
    acc.y = fmaf(p2, bf2f(v2.y), acc.y);
    acc.z = fmaf(p2, bf2f(v2.z), acc.z);
    acc.w = fmaf(p2, bf2f(v2.w), acc.w);
    acc.x = fmaf(p3, bf2f(v3.x), acc.x);
    acc.y = fmaf(p3, bf2f(v3.y), acc.y);
    acc.z = fmaf(p3, bf2f(v3.z), acc.z);
    acc.w = fmaf(p3, bf2f(v3.w), acc.w);
    den += p0 + p1 + p2 + p3;
  }
  for (; i < len; ++i) {
    int s0 = row[i];
    float ea = e2s[s0 * 4 + hd] + edn;
    float p0 = __expf(ea > 0.f ? ea : NEG * ea);
    uv4 v0 = *(const uv4*)(g2b + (size_t)s0 * 16 + hd * 4);
    acc.x = fmaf(p0, bf2f(v0.x), acc.x);
    acc.y = fmaf(p0, bf2f(v0.y), acc.y);
    acc.z = fmaf(p0, bf2f(v0.z), acc.z);
    acc.w = fmaf(p0, bf2f(v0.w), acc.w);
    den += p0;
  }
  float inv = 1.f / den;
  const float* bp = b2 + hd * 4;
  float4 o;
  o.x = fmaxf(fmaf(acc.x, inv, bp[0]), 0.f);
  o.y = fmaxf(fmaf(acc.y, inv, bp[1]), 0.f);
  o.z = fmaxf(fmaf(acc.z, inv, bp[2]), 0.f);
  o.w = fmaxf(fmaf(acc.w, inv, bp[3]), 0.f);
  *(float4*)(h2 + (size_t)gid * 4) = o;
}

// -------- fused mean-pool + FC: one block per graph, no atomics --------
__global__ __launch_bounds__(256) void k_poolfc(const float* __restrict__ h2,
                                                const int* __restrict__ batch,
                                                const float* __restrict__ Wfc,
                                                const float* __restrict__ bfc,
                                                float* __restrict__ out, int N) {
  __shared__ float ls[16][17];
  __shared__ float mean[16];
  __shared__ int bounds[2];
  const int g = blockIdx.x;
  const int t = threadIdx.x;
  if (t < 2) {
    int target = g + t;
    int lo = 0, hi = N;
    while (lo < hi) {
      int mid = (lo + hi) >> 1;
      if (batch[mid] < target) lo = mid + 1; else hi = mid;
    }
    bounds[t] = lo;
  }
  __syncthreads();
  const int start = bounds[0], end = bounds[1];
  const int c = t & 15, rg = t >> 4;
  float s = 0.f;
  for (int r = start + rg; r < end; r += 16) s += h2[(size_t)r * 16 + c];
  ls[rg][c] = s;
  __syncthreads();
  if (t < 16) {
    float sum = 0.f;
#pragma unroll
    for (int i = 0; i < 16; ++i) sum += ls[i][t];
    mean[t] = sum / fmaxf((float)(end - start), 1.f);
  }
  __syncthreads();
  if (t < 10) {
    float s2 = bfc[t];
#pragma unroll
    for (int k = 0; k < 16; ++k) s2 = fmaf(mean[k], Wfc[k * 10 + t], s2);
    out[g * 10 + t] = s2;
  }
}

extern "C" void kernel_launch(void* const* d_in, const int* in_sizes, int n_in,
                              void* d_out, int out_size, void* d_ws, size_t ws_size,
                              hipStream_t stream) {
  const float* x   = (const float*)d_in[0];
  const int*   ei  = (const int*)d_in[1];
  const int*   bat = (const int*)d_in[2];
  const float* W1  = (const float*)d_in[3];
  const float* a1s = (const float*)d_in[4];
  const float* a1d = (const float*)d_in[5];
  const float* b1  = (const float*)d_in[6];
  const float* W2  = (const float*)d_in[7];
  const float* a2s = (const float*)d_in[8];
  const float* a2d = (const float*)d_in[9];
  const float* b2  = (const float*)d_in[10];
  const float* Wfc = (const float*)d_in[11];
  const float* bfc = (const float*)d_in[12];
  const int N = in_sizes[2];
  const int E = in_sizes[1] / 2;

  float* ws = (float*)d_ws;
  // [0,16N): g1b bf16(32N); reused: g2b bf16(16N) at [0,8N) + e2s/e2d
  unsigned short* g1b = (unsigned short*)ws;
  unsigned short* g2b = (unsigned short*)ws;
  float* e2s  = ws + (size_t)8 * N;
  float* e2d  = ws + (size_t)12 * N;
  // [16N,24N): e1s, e1d
  float* e1s  = ws + (size_t)16 * N;
  float* e1d  = ws + (size_t)20 * N;
  // [24N,56N): h1 fp32; h2 (16N) reuses it
  float* h1   = ws + (size_t)24 * N;
  float* h2   = ws + (size_t)24 * N;
  // ints: cursor[1024] + rowbase[N] + deg[N] + bins[K*CAP]
  int* cursor  = (int*)(ws + (size_t)56 * N);
  int* rowbase = cursor + 1024;
  int* deg     = rowbase + N;
  int* bins    = deg + N;

  const int K = (N + BKT - 1) >> SHIFT;        // dst buckets (<=1024 assumed)
  long long availInts = (long long)(ws_size / 4) - 56LL * N - 1024 - 2LL * N;
  long long capLL = availInts / K;
  // mean bucket load = E/K (~4092); multinomial sd ~64 -> 6144 is >30 sigma
  int CAP = (capLL > 6144) ? 6144 : (int)capLL;
  if (CAP < 1024) CAP = 1024;                   // degraded best-effort

  (void)hipMemsetAsync((void*)cursor, 0, 1024 * sizeof(int), stream);

  const int nb = (E + 4095) >> 12;              // one batch per block
  k_bin<<<nb, 256, 0, stream>>>(ei, E, K, CAP, cursor, bins);
  k_sort<<<K, 256, 0, stream>>>(bins, cursor, CAP, N, rowbase, deg);
  k_gemm1<<<(N + 63) / 64, 256, 0, stream>>>(x, W1, a1s, a1d, g1b, e1s, e1d, N);
  k_agg1<<<(N * 8 + 255) / 256, 256, 0, stream>>>(rowbase, deg, bins, e1s, e1d, g1b, b1, h1, N);
  k_gemm2<<<(N + 63) / 64, 256, 0, stream>>>(h1, W2, a2s, a2d, g2b, e2s, e2d, N);
  k_agg2<<<(N * 4 + 255) / 256, 256, 0, stream>>>(rowbase, deg, bins, e2s, e2d, g2b, b2, h2, N);
  k_poolfc<<<64, 256, 0, stream>>>(h2, bat, Wfc, bfc, (float*)d_out, N);
}

// Round 18
// 304.136 us; speedup vs baseline: 1.0387x; 1.0387x over previous
//
#include <hip/hip_runtime.h>
#include <hip/hip_bf16.h>

#define HEADS 4
#define NEG 0.2f
#define SHIFT 7
#define BKT 128           // nodes per bucket = 1<<SHIFT

typedef float fv4 __attribute__((ext_vector_type(4)));
typedef unsigned short uv4 __attribute__((ext_vector_type(4)));
typedef unsigned short uv8 __attribute__((ext_vector_type(8)));

static __device__ __forceinline__ unsigned short f2bf(float f) {
  unsigned u = __float_as_uint(f);
  u += 0x7FFFu + ((u >> 16) & 1u);   // round-to-nearest-even
  return (unsigned short)(u >> 16);
}
static __device__ __forceinline__ float bf2f(unsigned short h) {
  return __uint_as_float((unsigned)h << 16);
}

// ---- pass1: radix-bin edges by dst>>SHIFT, packed (src<<SHIFT|dst_local) ----
// grid=512 (measured best: 782 one-batch blocks regressed via cursor-atomic
// contention; the 2-batch tail hides under co-resident waves).
__global__ __launch_bounds__(256) void k_bin(const int* __restrict__ ei, int E,
                                             int K, int CAP,
                                             int* __restrict__ cursor,
                                             int* __restrict__ bins) {
  __shared__ int lcnt[1024];
  __shared__ int gbase[1024];
  const int t = threadIdx.x;
  const int nb = (E + 4095) >> 12;
  for (int batch = blockIdx.x; batch < nb; batch += gridDim.x) {
    const int e0 = batch << 12;
    for (int i = t; i < K; i += 256) lcnt[i] = 0;
    __syncthreads();
    int sreg[16], dreg[16], rank[16];
#pragma unroll
    for (int j = 0; j < 16; ++j) {
      int e = e0 + j * 256 + t;
      dreg[j] = -1;
      if (e < E) {
        sreg[j] = ei[e];
        dreg[j] = ei[E + e];
        rank[j] = atomicAdd(&lcnt[dreg[j] >> SHIFT], 1);
      }
    }
    __syncthreads();
    for (int i = t; i < K; i += 256)
      gbase[i] = (lcnt[i] > 0) ? atomicAdd(&cursor[i], lcnt[i]) : 0;
    __syncthreads();
#pragma unroll
    for (int j = 0; j < 16; ++j) {
      if (dreg[j] >= 0) {
        int b = dreg[j] >> SHIFT;
        int slot = gbase[b] + rank[j];
        if (slot < CAP)
          bins[(size_t)b * CAP + slot] = (sreg[j] << SHIFT) | (dreg[j] & (BKT - 1));
      }
    }
    __syncthreads();
  }
}

// ---- pass2: LDS counting-sort per bucket, in-place, coalesced writeback ----
__global__ __launch_bounds__(256) void k_sort(int* __restrict__ bins,
                                              const int* __restrict__ cursor,
                                              int CAP, int N,
                                              int* __restrict__ rowbase,
                                              int* __restrict__ deg) {
  __shared__ int ebuf[6144];
  __shared__ int sbuf[6144];
  __shared__ int hist[BKT], pre[BKT], cur[BKT];
  const int b = blockIdx.x;
  const int base = b << SHIFT;
  const int t = threadIdx.x;
  int total = cursor[b]; if (total > CAP) total = CAP;
  int* gsrc = bins + (size_t)b * CAP;
  for (int i = t; i < total; i += 256) ebuf[i] = gsrc[i];
  if (t < BKT) hist[t] = 0;
  __syncthreads();
  for (int i = t; i < total; i += 256) atomicAdd(&hist[ebuf[i] & (BKT - 1)], 1);
  __syncthreads();
  if (t < BKT) pre[t] = hist[t];
  __syncthreads();
  for (int off = 1; off < BKT; off <<= 1) {
    int v = (t < BKT && t >= off) ? pre[t - off] : 0;
    __syncthreads();
    if (t < BKT) pre[t] += v;
    __syncthreads();
  }
  if (t < BKT) {
    int ex = pre[t] - hist[t];      // exclusive prefix
    cur[t] = ex;
    int n = base + t;
    if (n < N) { rowbase[n] = b * CAP + ex; deg[n] = hist[t]; }
  }
  __syncthreads();
  for (int i = t; i < total; i += 256) {
    int pk = ebuf[i];
    int r = atomicAdd(&cur[pk & (BKT - 1)], 1);
    sbuf[r] = pk >> SHIFT;           // store plain src id
  }
  __syncthreads();
  for (int i = t; i < total; i += 256) gsrc[i] = sbuf[i];
}

// ---------------- GEMM1: g1b = bf16(x @ W1), fused e-scores ----------------
// 64-row tile (25.4 KB LDS, 6 blocks/CU) + register prefetch of chunk k+1.
__global__ __launch_bounds__(256) void k_gemm1(const float* __restrict__ x,
                                               const float* __restrict__ W,
                                               const float* __restrict__ a1s,
                                               const float* __restrict__ a1d,
                                               unsigned short* __restrict__ g1b,
                                               float* __restrict__ e1s,
                                               float* __restrict__ e1d, int N) {
  __shared__ __align__(16) float xs[64][68];
  __shared__ __align__(16) float ws[64][32];
  const int t = threadIdx.x;
  const int n0 = blockIdx.x * 64;
  const int nl = t >> 2;   // node within tile
  const int cg = t & 3;    // head, cols 8cg..8cg+7
  float acc[8];
#pragma unroll
  for (int j = 0; j < 8; ++j) acc[j] = 0.f;
  const int r = t >> 4;
  const int kk = (t & 15) << 2;
  fv4 xr[4];
  float4 wr0, wr1;
#pragma unroll
  for (int i = 0; i < 4; ++i) {
    int gn = n0 + r + i * 16;
    fv4 v = {0.f, 0.f, 0.f, 0.f};
    if (gn < N) v = __builtin_nontemporal_load((const fv4*)(x + (size_t)gn * 512 + kk));
    xr[i] = v;
  }
  wr0 = ((const float4*)W)[t];
  wr1 = ((const float4*)W)[t + 256];
  for (int kc = 0; kc < 512; kc += 64) {
    __syncthreads();
#pragma unroll
    for (int i = 0; i < 4; ++i) *(fv4*)(&xs[r + i * 16][kk]) = xr[i];
    ((float4*)ws)[t] = wr0;
    ((float4*)ws)[t + 256] = wr1;
    __syncthreads();
    const int kn = kc + 64;
    if (kn < 512) {
#pragma unroll
      for (int i = 0; i < 4; ++i) {
        int gn = n0 + r + i * 16;
        fv4 v = {0.f, 0.f, 0.f, 0.f};
        if (gn < N) v = __builtin_nontemporal_load((const fv4*)(x + (size_t)gn * 512 + kn + kk));
        xr[i] = v;
      }
      wr0 = ((const float4*)(W + kn * 32))[t];
      wr1 = ((const float4*)(W + kn * 32))[t + 256];
    }
#pragma unroll
    for (int k = 0; k < 64; ++k) {
      float xv = xs[nl][k];
      float4 w0 = *(const float4*)(&ws[k][cg * 8]);
      float4 w1 = *(const float4*)(&ws[k][cg * 8 + 4]);
      acc[0] = fmaf(xv, w0.x, acc[0]);
      acc[1] = fmaf(xv, w0.y, acc[1]);
      acc[2] = fmaf(xv, w0.z, acc[2]);
      acc[3] = fmaf(xv, w0.w, acc[3]);
      acc[4] = fmaf(xv, w1.x, acc[4]);
      acc[5] = fmaf(xv, w1.y, acc[5]);
      acc[6] = fmaf(xv, w1.z, acc[6]);
      acc[7] = fmaf(xv, w1.w, acc[7]);
    }
  }
  int gn = n0 + nl;
  if (gn < N) {
    uv8 pk;
#pragma unroll
    for (int j = 0; j < 8; ++j) pk[j] = f2bf(acc[j]);
    *(uv8*)(g1b + (size_t)gn * 32 + cg * 8) = pk;
    const float* as = a1s + cg * 8;
    const float* ad = a1d + cg * 8;
    float s = 0.f, d = 0.f;
#pragma unroll
    for (int j = 0; j < 8; ++j) { s = fmaf(acc[j], as[j], s); d = fmaf(acc[j], ad[j], d); }
    e1s[gn * 4 + cg] = s;
    e1d[gn * 4 + cg] = d;
  }
}

// ---- conv1 aggregation: 8 lanes per node, gather-only, 4x unrolled ----
__global__ __launch_bounds__(256) void k_agg1(const int* __restrict__ rowbase,
                                              const int* __restrict__ deg,
                                              const int* __restrict__ csr,
                                              const float* __restrict__ e1s,
                                              const float* __restrict__ e1d,
                                              const unsigned short* __restrict__ g1b,
                                              const float* __restrict__ b1,
                                              float* __restrict__ h1, int N) {
  int gid = blockIdx.x * blockDim.x + threadIdx.x;
  if (gid >= N * 8) return;
  int n = gid >> 3, cg = gid & 7, hd = cg >> 1;
  float edn = e1d[n * 4 + hd];
  // self-loop
  float s = e1s[n * 4 + hd] + edn;
  float p = __expf(s > 0.f ? s : NEG * s);
  uv4 hv = *(const uv4*)(g1b + (size_t)n * 32 + cg * 4);
  float4 acc = make_float4(p * bf2f(hv.x), p * bf2f(hv.y), p * bf2f(hv.z), p * bf2f(hv.w));
  float den = p;
  int beg = rowbase[n], len = deg[n];
  const int* row = csr + beg;
  int i = 0;
  for (; i + 4 <= len; i += 4) {           // 4 independent gathers in flight
    int s0 = row[i], s1 = row[i + 1], s2 = row[i + 2], s3 = row[i + 3];
    float ea = e1s[s0 * 4 + hd] + edn;
    float eb = e1s[s1 * 4 + hd] + edn;
    float ec = e1s[s2 * 4 + hd] + edn;
    float ed = e1s[s3 * 4 + hd] + edn;
    uv4 v0 = *(const uv4*)(g1b + (size_t)s0 * 32 + cg * 4);
    uv4 v1 = *(const uv4*)(g1b + (size_t)s1 * 32 + cg * 4);
    uv4 v2 = *(const uv4*)(g1b + (size_t)s2 * 32 + cg * 4);
    uv4 v3 = *(const uv4*)(g1b + (size_t)s3 * 32 + cg * 4);
    float p0 = __expf(ea > 0.f ? ea : NEG * ea);
    float p1 = __expf(eb > 0.f ? eb : NEG * eb);
    float p2 = __expf(ec > 0.f ? ec : NEG * ec);
    float p3 = __expf(ed > 0.f ? ed : NEG * ed);
    acc.x = fmaf(p0, bf2f(v0.x), acc.x);
    acc.y = fmaf(p0, bf2f(v0.y), acc.y);
    acc.z = fmaf(p0, bf2f(v0.z), acc.z);
    acc.w = fmaf(p0, bf2f(v0.w), acc.w);
    acc.x = fmaf(p1, bf2f(v1.x), acc.x);
    acc.y = fmaf(p1, bf2f(v1.y), acc.y);
    acc.z = fmaf(p1, bf2f(v1.z), acc.z);
    acc.w = fmaf(p1, bf2f(v1.w), acc.w);
    acc.x = fmaf(p2, bf2f(v2.x), acc.x);
    acc.y = fmaf(p2, bf2f(v2.y), acc.y);
    acc.z = fmaf(p2, bf2f(v2.z), acc.z);
    acc.w = fmaf(p2, bf2f(v2.w), acc.w);
    acc.x = fmaf(p3, bf2f(v3.x), acc.x);
    acc.y = fmaf(p3, bf2f(v3.y), acc.y);
    acc.z = fmaf(p3, bf2f(v3.z), acc.z);
    acc.w = fmaf(p3, bf2f(v3.w), acc.w);
    den += p0 + p1 + p2 + p3;
  }
  for (; i < len; ++i) {
    int s0 = row[i];
    float ea = e1s[s0 * 4 + hd] + edn;
    float p0 = __expf(ea > 0.f ? ea : NEG * ea);
    uv4 v0 = *(const uv4*)(g1b + (size_t)s0 * 32 + cg * 4);
    acc.x = fmaf(p0, bf2f(v0.x), acc.x);
    acc.y = fmaf(p0, bf2f(v0.y), acc.y);
    acc.z = fmaf(p0, bf2f(v0.z), acc.z);
    acc.w = fmaf(p0, bf2f(v0.w), acc.w);
    den += p0;
  }
  float inv = 1.f / den;
  const float* bp = b1 + cg * 4;
  float4 o;
  o.x = fmaxf(fmaf(acc.x, inv, bp[0]), 0.f);
  o.y = fmaxf(fmaf(acc.y, inv, bp[1]), 0.f);
  o.z = fmaxf(fmaf(acc.z, inv, bp[2]), 0.f);
  o.w = fmaxf(fmaf(acc.w, inv, bp[3]), 0.f);
  *(float4*)(h1 + (size_t)gid * 4) = o;
}

// ---- GEMM2 (fused e2 scores): g2b = bf16(h1 @ W2) ----
__global__ __launch_bounds__(256) void k_gemm2(const float* __restrict__ h1,
                                               const float* __restrict__ W2,
                                               const float* __restrict__ a2s_,
                                               const float* __restrict__ a2d_,
                                               unsigned short* __restrict__ g2b,
                                               float* __restrict__ e2s,
                                               float* __restrict__ e2d, int N) {
  __shared__ __align__(16) float hs[64][36];
  __shared__ __align__(16) float ws[32][16];
  const int t = threadIdx.x;
  const int n0 = blockIdx.x * 64;
  {
    int row = t >> 3, c4 = (t & 7) * 4;
#pragma unroll
    for (int i = 0; i < 2; ++i) {
      int rr = row + i * 32;
      int gn = n0 + rr;
      float4 v = make_float4(0.f, 0.f, 0.f, 0.f);
      if (gn < N) v = *(const float4*)(h1 + (size_t)gn * 32 + c4);
      *(float4*)(&hs[rr][c4]) = v;
    }
    if (t < 128) ((float4*)ws)[t] = ((const float4*)W2)[t];
  }
  __syncthreads();
  const int nl = t >> 2, cg = t & 3;   // head = cg
  float acc[4] = {0.f, 0.f, 0.f, 0.f};
#pragma unroll
  for (int k = 0; k < 32; ++k) {
    float xv = hs[nl][k];
    float4 w = *(const float4*)(&ws[k][cg * 4]);
    acc[0] = fmaf(xv, w.x, acc[0]);
    acc[1] = fmaf(xv, w.y, acc[1]);
    acc[2] = fmaf(xv, w.z, acc[2]);
    acc[3] = fmaf(xv, w.w, acc[3]);
  }
  int gn = n0 + nl;
  if (gn < N) {
    uv4 pk;
#pragma unroll
    for (int j = 0; j < 4; ++j) pk[j] = f2bf(acc[j]);
    *(uv4*)(g2b + (size_t)gn * 16 + cg * 4) = pk;
    const float* as = a2s_ + cg * 4;
    const float* ad = a2d_ + cg * 4;
    e2s[gn * 4 + cg] = acc[0] * as[0] + acc[1] * as[1] + acc[2] * as[2] + acc[3] * as[3];
    e2d[gn * 4 + cg] = acc[0] * ad[0] + acc[1] * ad[1] + acc[2] * ad[2] + acc[3] * ad[3];
  }
}

// ---- conv2 aggregation: 4 lanes per node, gather-only, 4x unrolled ----
__global__ __launch_bounds__(256) void k_agg2(const int* __restrict__ rowbase,
                                              const int* __restrict__ deg,
                                              const int* __restrict__ csr,
                                              const float* __restrict__ e2s,
                                              const float* __restrict__ e2d,
                                              const unsigned short* __restrict__ g2b,
                                              const float* __restrict__ b2,
                                              float* __restrict__ h2, int N) {
  int gid = blockIdx.x * blockDim.x + threadIdx.x;
  if (gid >= N * 4) return;
  int n = gid >> 2, hd = gid & 3;
  float edn = e2d[n * 4 + hd];
  float s = e2s[n * 4 + hd] + edn;
  float p = __expf(s > 0.f ? s : NEG * s);
  uv4 hv = *(const uv4*)(g2b + (size_t)n * 16 + hd * 4);
  float4 acc = make_float4(p * bf2f(hv.x), p * bf2f(hv.y), p * bf2f(hv.z), p * bf2f(hv.w));
  float den = p;
  int beg = rowbase[n], len = deg[n];
  const int* row = csr + beg;
  int i = 0;
  for (; i + 4 <= len; i += 4) {
    int s0 = row[i], s1 = row[i + 1], s2 = row[i + 2], s3 = row[i + 3];
    float ea = e2s[s0 * 4 + hd] + edn;
    float eb = e2s[s1 * 4 + hd] + edn;
    float ec = e2s[s2 * 4 + hd] + edn;
    float ed = e2s[s3 * 4 + hd] + edn;
    uv4 v0 = *(const uv4*)(g2b + (size_t)s0 * 16 + hd * 4);
    uv4 v1 = *(const uv4*)(g2b + (size_t)s1 * 16 + hd * 4);
    uv4 v2 = *(const uv4*)(g2b + (size_t)s2 * 16 + hd * 4);
    uv4 v3 = *(const uv4*)(g2b + (size_t)s3 * 16 + hd * 4);
    float p0 = __expf(ea > 0.f ? ea : NEG * ea);
    float p1 = __expf(eb > 0.f ? eb : NEG * eb);
    float p2 = __expf(ec > 0.f ? ec : NEG * ec);
    float p3 = __expf(ed > 0.f ? ed : NEG * ed);
    acc.x = fmaf(p0, bf2f(v0.x), acc.x);
    acc.y = fmaf(p0, bf2f(v0.y), acc.y);
    acc.z = fmaf(p0, bf2f(v0.z), acc.z);
    acc.w = fmaf(p0, bf2f(v0.w), acc.w);
    acc.x = fmaf(p1, bf2f(v1.x), acc.x);
    acc.y = fmaf(p1, bf2f(v1.y), acc.y);
    acc.z = fmaf(p1, bf2f(v1.z), acc.z);
    acc.w = fmaf(p1, bf2f(v1.w), acc.w);
    acc.x = fmaf(p2, bf2f(v2.x), acc.x);
    acc.y = fmaf(p2, bf2f(v2.y), acc.y);
    acc.z = fmaf(p2, bf2f(v2.z), acc.z);
    acc.w = fmaf(p2, bf2f(v2.w), acc.w);
    acc.x = fmaf(p3, bf2f(v3.x), acc.x);
    acc.y = fmaf(p3, bf2f(v3.y), acc.y);
    acc.z = fmaf(p3, bf2f(v3.z), acc.z);
    acc.w = fmaf(p3, bf2f(v3.w), acc.w);
    den += p0 + p1 + p2 + p3;
  }
  for (; i < len; ++i) {
    int s0 = row[i];
    float ea = e2s[s0 * 4 + hd] + edn;
    float p0 = __expf(ea > 0.f ? ea : NEG * ea);
    uv4 v0 = *(const uv4*)(g2b + (size_t)s0 * 16 + hd * 4);
    acc.x = fmaf(p0, bf2f(v0.x), acc.x);
    acc.y = fmaf(p0, bf2f(v0.y), acc.y);
    acc.z = fmaf(p0, bf2f(v0.z), acc.z);
    acc.w = fmaf(p0, bf2f(v0.w), acc.w);
    den += p0;
  }
  float inv = 1.f / den;
  const float* bp = b2 + hd * 4;
  float4 o;
  o.x = fmaxf(fmaf(acc.x, inv, bp[0]), 0.f);
  o.y = fmaxf(fmaf(acc.y, inv, bp[1]), 0.f);
  o.z = fmaxf(fmaf(acc.z, inv, bp[2]), 0.f);
  o.w = fmaxf(fmaf(acc.w, inv, bp[3]), 0.f);
  *(float4*)(h2 + (size_t)gid * 4) = o;
}

// -------- fused mean-pool + FC: one block per graph, no atomics --------
__global__ __launch_bounds__(256) void k_poolfc(const float* __restrict__ h2,
                                                const int* __restrict__ batch,
                                                const float* __restrict__ Wfc,
                                                const float* __restrict__ bfc,
                                                float* __restrict__ out, int N) {
  __shared__ float ls[16][17];
  __shared__ float mean[16];
  __shared__ int bounds[2];
  const int g = blockIdx.x;
  const int t = threadIdx.x;
  if (t < 2) {
    int target = g + t;
    int lo = 0, hi = N;
    while (lo < hi) {
      int mid = (lo + hi) >> 1;
      if (batch[mid] < target) lo = mid + 1; else hi = mid;
    }
    bounds[t] = lo;
  }
  __syncthreads();
  const int start = bounds[0], end = bounds[1];
  const int c = t & 15, rg = t >> 4;
  float s = 0.f;
  for (int r = start + rg; r < end; r += 16) s += h2[(size_t)r * 16 + c];
  ls[rg][c] = s;
  __syncthreads();
  if (t < 16) {
    float sum = 0.f;
#pragma unroll
    for (int i = 0; i < 16; ++i) sum += ls[i][t];
    mean[t] = sum / fmaxf((float)(end - start), 1.f);
  }
  __syncthreads();
  if (t < 10) {
    float s2 = bfc[t];
#pragma unroll
    for (int k = 0; k < 16; ++k) s2 = fmaf(mean[k], Wfc[k * 10 + t], s2);
    out[g * 10 + t] = s2;
  }
}

extern "C" void kernel_launch(void* const* d_in, const int* in_sizes, int n_in,
                              void* d_out, int out_size, void* d_ws, size_t ws_size,
                              hipStream_t stream) {
  const float* x   = (const float*)d_in[0];
  const int*   ei  = (const int*)d_in[1];
  const int*   bat = (const int*)d_in[2];
  const float* W1  = (const float*)d_in[3];
  const float* a1s = (const float*)d_in[4];
  const float* a1d = (const float*)d_in[5];
  const float* b1  = (const float*)d_in[6];
  const float* W2  = (const float*)d_in[7];
  const float* a2s = (const float*)d_in[8];
  const float* a2d = (const float*)d_in[9];
  const float* b2  = (const float*)d_in[10];
  const float* Wfc = (const float*)d_in[11];
  const float* bfc = (const float*)d_in[12];
  const int N = in_sizes[2];
  const int E = in_sizes[1] / 2;

  float* ws = (float*)d_ws;
  // [0,16N): g1b bf16(32N); reused: g2b bf16(16N) at [0,8N) + e2s/e2d
  unsigned short* g1b = (unsigned short*)ws;
  unsigned short* g2b = (unsigned short*)ws;
  float* e2s  = ws + (size_t)8 * N;
  float* e2d  = ws + (size_t)12 * N;
  // [16N,24N): e1s, e1d
  float* e1s  = ws + (size_t)16 * N;
  float* e1d  = ws + (size_t)20 * N;
  // [24N,56N): h1 fp32; h2 (16N) reuses it
  float* h1   = ws + (size_t)24 * N;
  float* h2   = ws + (size_t)24 * N;
  // ints: cursor[1024] + rowbase[N] + deg[N] + bins[K*CAP]
  int* cursor  = (int*)(ws + (size_t)56 * N);
  int* rowbase = cursor + 1024;
  int* deg     = rowbase + N;
  int* bins    = deg + N;

  const int K = (N + BKT - 1) >> SHIFT;        // dst buckets (<=1024 assumed)
  long long availInts = (long long)(ws_size / 4) - 56LL * N - 1024 - 2LL * N;
  long long capLL = availInts / K;
  // mean bucket load = E/K (~4092); multinomial sd ~64 -> 6144 is >30 sigma
  int CAP = (capLL > 6144) ? 6144 : (int)capLL;
  if (CAP < 1024) CAP = 1024;                   // degraded best-effort

  (void)hipMemsetAsync((void*)cursor, 0, 1024 * sizeof(int), stream);

  k_bin<<<512, 256, 0, stream>>>(ei, E, K, CAP, cursor, bins);
  k_sort<<<K, 256, 0, stream>>>(bins, cursor, CAP, N, rowbase, deg);
  k_gemm1<<<(N + 63) / 64, 256, 0, stream>>>(x, W1, a1s, a1d, g1b, e1s, e1d, N);
  k_agg1<<<(N * 8 + 255) / 256, 256, 0, stream>>>(rowbase, deg, bins, e1s, e1d, g1b, b1, h1, N);
  k_gemm2<<<(N + 63) / 64, 256, 0, stream>>>(h1, W2, a2s, a2d, g2b, e2s, e2d, N);
  k_agg2<<<(N * 4 + 255) / 256, 256, 0, stream>>>(rowbase, deg, bins, e2s, e2d, g2b, b2, h2, N);
  k_poolfc<<<64, 256, 0, stream>>>(h2, bat, Wfc, bfc, (float*)d_out, N);
}